// Round 11
// baseline (3528.674 us; speedup 1.0000x reference)
//
#include <hip/hip_runtime.h>

#define FEAT 128
#define NSLICE 64
#define NPC 51200          // padded node count (problem-fixed N=50000)
#define RANGE_F 25600      // fill cursor tile (2 range passes)

// fused-layer dynamic LDS layout (bytes)
#define MS_OFF    0            // 64*132 f32   = 33792
#define W16_OFF   33792        // 16384 f16    = 32768
#define WR_OFF    66560        // 16384 f16    = 32768
#define EDST_OFF  99328        // 4096 int     = 16384
#define OFFS_OFF  115712       // 68 int       = 272
#define LDS_TOTAL 115984

typedef _Float16 half8 __attribute__((ext_vector_type(8)));
typedef float f32x4 __attribute__((ext_vector_type(4)));

// ---------- hist: one pass, full-node packed histogram in 102.4KB dynamic LDS ----------
__global__ __launch_bounds__(1024) void hist_kernel(const int* __restrict__ src,
                                                    const int* __restrict__ dst,
                                                    unsigned* __restrict__ partialD,
                                                    unsigned* __restrict__ partialS,
                                                    int E) {
    extern __shared__ unsigned hpk[];                // NPC/2 = 25600 words
    int b = blockIdx.x;
    int halfsel = b >> 6;
    int s = b & 63;
    const int* arr = halfsel ? src : dst;
    unsigned* out = halfsel ? partialS : partialD;
    int tid = threadIdx.x;
    for (int i = tid; i < NPC / 2; i += 1024) hpk[i] = 0;
    __syncthreads();
    int e0 = (int)((long long)E * s / NSLICE);
    int e1 = (int)((long long)E * (s + 1) / NSLICE);
    for (int e = e0 + tid; e < e1; e += 1024) {
        unsigned d = (unsigned)arr[e];
        atomicAdd(&hpk[d >> 1], (d & 1) ? 65536u : 1u);
    }
    __syncthreads();
    size_t wbase = ((size_t)s * NPC) >> 1;
    for (int i = tid; i < NPC / 2; i += 1024) out[wbase + i] = hpk[i];
}

// ---------- prep1: blocks [0,sb): slice sums + norms + blockSums
//                   blocks [sb, sb+320): W fp16 value+residual transpose ----------
__global__ __launch_bounds__(256) void prep1_kernel(const unsigned short* __restrict__ pD,
                                                    const unsigned short* __restrict__ pS,
                                                    int* __restrict__ blockSums,
                                                    float* __restrict__ ns,
                                                    float* __restrict__ nd,
                                                    const float* __restrict__ Wa,
                                                    const float* __restrict__ Wb,
                                                    const float* __restrict__ Wc,
                                                    const float* __restrict__ Wd,
                                                    const float* __restrict__ We,
                                                    _Float16* __restrict__ w16t,
                                                    _Float16* __restrict__ wrt,
                                                    int n, int sb) {
    int tid = threadIdx.x;
    int b = blockIdx.x;
    if (b < sb) {
        __shared__ int buf[256];
        int v = b * 256 + tid;
        int ssum = 0, osum = 0;
        #pragma unroll
        for (int s = 0; s < NSLICE; ++s) {
            ssum += pD[(size_t)s * NPC + v];
            osum += pS[(size_t)s * NPC + v];
        }
        if (v < n) {
            ns[v] = 1.0f / sqrtf((float)(osum < 1 ? 1 : osum));
            nd[v] = 1.0f / sqrtf((float)(ssum < 1 ? 1 : ssum));
        }
        buf[tid] = ssum;
        __syncthreads();
        #pragma unroll
        for (int off = 1; off < 256; off <<= 1) {
            int t = (tid >= off) ? buf[tid - off] : 0;
            __syncthreads();
            buf[tid] += t;
            __syncthreads();
        }
        if (tid == 255) blockSums[b] = buf[255];
    } else {
        int gid = (b - sb) * 256 + tid;              // 0 .. 81919
        int l = gid >> 14;
        int idx = gid & 16383;
        int col = idx >> 7;
        int k = idx & 127;
        const float* Wp = (l == 0) ? Wa : (l == 1) ? Wb : (l == 2) ? Wc : (l == 3) ? Wd : We;
        float w = Wp[k * FEAT + col];
        _Float16 h = (_Float16)w;
        _Float16 r = (_Float16)(w - (float)h);
        w16t[gid] = h;
        wrt[gid] = r;
    }
}

// ---------- prep2: blocks [0,nb): merged scan2+scan3, cursorVT [slice][node] layout
//                   blocks [nb, ...): prescale xh = fp16(in_feat * ns) ----------
__global__ __launch_bounds__(256) void prep2_kernel(const unsigned short* __restrict__ pD,
                                                    const int* __restrict__ blockSums,
                                                    int* __restrict__ cursorVT,
                                                    int* __restrict__ offsc,
                                                    const float* __restrict__ xf,
                                                    const float* __restrict__ ns,
                                                    _Float16* __restrict__ xh,
                                                    int n, int nb) {
    int tid = threadIdx.x;
    int b = blockIdx.x;
    if (b < nb) {
        __shared__ int buf[256];
        int bsv = (tid < nb) ? blockSums[tid] : 0;
        buf[tid] = bsv;
        __syncthreads();
        #pragma unroll
        for (int off = 1; off < 256; off <<= 1) {
            int t = (tid >= off) ? buf[tid - off] : 0;
            __syncthreads();
            buf[tid] += t;
            __syncthreads();
        }
        int myoff = (b > 0) ? buf[b - 1] : 0;
        __syncthreads();
        int v = b * 256 + tid;
        int ssum = 0;
        #pragma unroll
        for (int s = 0; s < NSLICE; ++s) ssum += pD[(size_t)s * NPC + v];
        buf[tid] = ssum;
        __syncthreads();
        #pragma unroll
        for (int off = 1; off < 256; off <<= 1) {
            int t = (tid >= off) ? buf[tid - off] : 0;
            __syncthreads();
            buf[tid] += t;
            __syncthreads();
        }
        int o = myoff + buf[tid] - ssum;
        if (v <= n) offsc[v] = o;      // pad nodes have zero edges -> v==n gets total
        #pragma unroll
        for (int s = 0; s < NSLICE; ++s) {
            int val = pD[(size_t)s * NPC + v];
            cursorVT[(size_t)s * NPC + v] = o;       // coalesced per-s
            o += val;
        }
    } else {
        int i = (b - nb) * 256 + tid;                // one thread per 8 elements
        if (i < n * (FEAT / 8)) {
            int v = i >> 4;
            float w = ns[v];
            float4 t0 = ((const float4*)xf)[i * 2];
            float4 t1 = ((const float4*)xf)[i * 2 + 1];
            half8 h;
            h[0] = (_Float16)(t0.x * w); h[1] = (_Float16)(t0.y * w);
            h[2] = (_Float16)(t0.z * w); h[3] = (_Float16)(t0.w * w);
            h[4] = (_Float16)(t1.x * w); h[5] = (_Float16)(t1.y * w);
            h[6] = (_Float16)(t1.z * w); h[7] = (_Float16)(t1.w * w);
            ((float4*)xh)[i] = __builtin_bit_cast(float4, h);
        }
    }
}

// ---------- fill: 2 range passes, contiguous cursor tile load, XCD-swizzled slices ----------
__global__ __launch_bounds__(1024) void fill_kernel(const int* __restrict__ src,
                                                    const int* __restrict__ dst,
                                                    const int* __restrict__ cursorVT,
                                                    int* __restrict__ esrc, int E) {
    extern __shared__ int cur[];                     // RANGE_F ints = 102.4KB
    int b = blockIdx.x;
    int r = b / NSLICE;
    int inner = b % NSLICE;
    int s = ((inner & 7) << 3) | (inner >> 3);
    int v0 = r * RANGE_F;
    int tid = threadIdx.x;
    const int4* csrc = (const int4*)(cursorVT + (size_t)s * NPC + v0);
    for (int i = tid; i < RANGE_F / 4; i += 1024)
        ((int4*)cur)[i] = csrc[i];
    __syncthreads();
    int e0 = (int)((long long)E * s / NSLICE);
    int e1 = (int)((long long)E * (s + 1) / NSLICE);
    for (int e = e0 + tid; e < e1; e += 1024) {
        unsigned dd = (unsigned)(dst[e] - v0);
        if (dd < RANGE_F) {
            int p = atomicAdd(&cur[dd], 1);
            esrc[p] = src[e];
        }
    }
}

// ---------- fused layer: edge-balanced gather into LDS m-tile + MFMA, one dispatch ----------
// Block owns 64 dst rows = one CONTIGUOUS esrc segment [offs[v0], offs[v0+64)).
// Phase 1: segment's edges split evenly over 32 16-lane groups; rows accumulate into
//          ms[64][132] fp32 via ds_add_f32 (edst[] maps edge -> local row).
// Phase 2: A-frag = fp16(ms * nd) in regs; W16/Wr LDS-staged; acc = A*W16 + A*Wr.
template<int MODE>   // 0: relu*ns -> fp16 xout   1: last layer (fp32 h + threshold)
__global__ __launch_bounds__(512) void layer_kernel(const _Float16* __restrict__ x,
                                                    const int* __restrict__ offs,
                                                    const int* __restrict__ esrc,
                                                    const float* __restrict__ nd,
                                                    const float* __restrict__ nsv,
                                                    const _Float16* __restrict__ w16t,
                                                    const _Float16* __restrict__ wrt,
                                                    const float* __restrict__ bias,
                                                    _Float16* __restrict__ outh,
                                                    float* __restrict__ outf,
                                                    float* __restrict__ out2, int n) {
    extern __shared__ char smem[];
    float*    ms     = (float*)(smem + MS_OFF);      // [64][132]
    _Float16* W16s   = (_Float16*)(smem + W16_OFF);
    _Float16* Wrs    = (_Float16*)(smem + WR_OFF);
    int*      edst   = (int*)(smem + EDST_OFF);      // 4096 entries
    int*      offs_s = (int*)(smem + OFFS_OFF);      // 65
    int tid = threadIdx.x;
    int r0 = blockIdx.x * 64;

    if (tid <= 64) {
        int v = r0 + tid;
        offs_s[tid] = offs[v > n ? n : v];
    }
    // stage W (value+residual), XOR-swizzled 16B chunks: chunk ^= (col&7)
    #pragma unroll
    for (int j = 0; j < 4; ++j) {
        int i = tid + j * 512;             // 2048 float4 per array
        int col = i >> 4, ch = i & 15;
        int d = col * 16 + (ch ^ (col & 7));
        ((float4*)W16s)[d] = ((const float4*)w16t)[i];
        ((float4*)Wrs)[d]  = ((const float4*)wrt)[i];
    }
    // zero m tile
    for (int i = tid; i < 64 * 132 / 4; i += 512)
        ((float4*)ms)[i] = make_float4(0.f, 0.f, 0.f, 0.f);
    __syncthreads();

    int base = offs_s[0];
    int end  = offs_s[64];
    // build edge -> local-row map (64 threads, ~16 writes each; balanced enough)
    if (tid < 64) {
        int b0 = offs_s[tid], b1 = offs_s[tid + 1];
        for (int j = b0; j < b1; ++j)
            if (j - base < 4096) edst[j - base] = tid;
    }
    __syncthreads();
    if (end - base > 4096) end = base + 4096;        // Poisson(1024): unreachable guard

    // ---- phase 1: edge-balanced gather ----
    int g = tid >> 4;                                // 32 groups
    int c = tid & 15;                                // 16 lanes x 16B cover a 128-half row
    int j = base + g;
    for (; j + 224 < end; j += 256) {                // 8 edges per group in flight
        int e[8], d[8];
        float4 rv[8];
        #pragma unroll
        for (int kk = 0; kk < 8; ++kk) {
            e[kk] = esrc[j + kk * 32];
            d[kk] = edst[j + kk * 32 - base];
        }
        #pragma unroll
        for (int kk = 0; kk < 8; ++kk)
            rv[kk] = ((const float4*)(x + (size_t)e[kk] * FEAT))[c];
        #pragma unroll
        for (int kk = 0; kk < 8; ++kk) {
            half8 h = __builtin_bit_cast(half8, rv[kk]);
            float* mrow = ms + d[kk] * 132 + c * 8;
            #pragma unroll
            for (int k = 0; k < 8; ++k)
                atomicAdd(&mrow[k], (float)h[k]);
        }
    }
    for (; j < end; j += 32) {
        int e0 = esrc[j];
        int d0 = edst[j - base];
        float4 rv = ((const float4*)(x + (size_t)e0 * FEAT))[c];
        half8 h = __builtin_bit_cast(half8, rv);
        float* mrow = ms + d0 * 132 + c * 8;
        #pragma unroll
        for (int k = 0; k < 8; ++k)
            atomicAdd(&mrow[k], (float)h[k]);
    }
    __syncthreads();

    // ---- phase 2: MFMA (8 waves: 4 row-groups x 2 col-groups) ----
    int lane = tid & 63;
    int w = tid >> 6;
    int l15 = lane & 15;
    int q = lane >> 4;
    int rw = w & 3, cw = w >> 2;
    int rbase = rw * 16 + l15;
    int rgl = r0 + rbase;
    float ndv = (rgl < n) ? nd[rgl] : 0.f;
    int cbase = cw * 64;

    f32x4 acc[4] = {{0.f,0.f,0.f,0.f},{0.f,0.f,0.f,0.f},{0.f,0.f,0.f,0.f},{0.f,0.f,0.f,0.f}};
    #pragma unroll
    for (int ks = 0; ks < 4; ++ks) {
        int chunk = ks * 4 + q;
        const float* mp = ms + rbase * 132 + chunk * 8;
        float4 f0 = *(const float4*)mp;
        float4 f1 = *(const float4*)(mp + 4);
        half8 a16;
        a16[0] = (_Float16)(f0.x * ndv); a16[1] = (_Float16)(f0.y * ndv);
        a16[2] = (_Float16)(f0.z * ndv); a16[3] = (_Float16)(f0.w * ndv);
        a16[4] = (_Float16)(f1.x * ndv); a16[5] = (_Float16)(f1.y * ndv);
        a16[6] = (_Float16)(f1.z * ndv); a16[7] = (_Float16)(f1.w * ndv);
        #pragma unroll
        for (int ct = 0; ct < 4; ++ct) {
            int col = cbase + ct * 16 + l15;
            int boff = col * 128 + ((chunk ^ (col & 7)) << 3);
            half8 b16 = *(const half8*)(W16s + boff);
            half8 br  = *(const half8*)(Wrs + boff);
            acc[ct] = __builtin_amdgcn_mfma_f32_16x16x32_f16(a16, b16, acc[ct], 0, 0, 0);
            acc[ct] = __builtin_amdgcn_mfma_f32_16x16x32_f16(a16, br,  acc[ct], 0, 0, 0);
        }
    }

    // epilogue via LDS restage (over W area) -> coalesced float4 stores
    // C/D layout: col=lane&15, row=(lane>>4)*4+reg
    int rloc = rw * 16 + q * 4;
    __syncthreads();                       // all MFMA reads of W16s/Wrs done
    if (MODE == 0) {
        _Float16* hstage = (_Float16*)(smem + W16_OFF);    // 64x128 fp16 = 16KB
        float scv[4];
        #pragma unroll
        for (int reg = 0; reg < 4; ++reg) {
            int row = r0 + rloc + reg;
            scv[reg] = (row < n) ? nsv[row] : 1.0f;
        }
        #pragma unroll
        for (int ct = 0; ct < 4; ++ct) {
            int col = cbase + ct * 16 + l15;
            float b = bias[col];
            #pragma unroll
            for (int reg = 0; reg < 4; ++reg) {
                float h = acc[ct][reg] + b;
                h = h > 0.f ? h : 0.f;
                hstage[(rloc + reg) * 128 + col] = (_Float16)(h * scv[reg]);
            }
        }
        __syncthreads();
        #pragma unroll
        for (int jj = 0; jj < 2; ++jj) {
            int i = tid + jj * 512;        // 1024 float4 (8 halves each)
            int row = i >> 4, c16 = i & 15;
            if (r0 + row < n)
                ((float4*)(outh + (size_t)(r0 + row) * FEAT))[c16] =
                    ((const float4*)hstage)[i];
        }
    } else {
        float* fstage = (float*)(smem + W16_OFF);          // 64x128 fp32 = 32KB
        #pragma unroll
        for (int ct = 0; ct < 4; ++ct) {
            int col = cbase + ct * 16 + l15;
            float b = bias[col];
            #pragma unroll
            for (int reg = 0; reg < 4; ++reg) {
                float h = acc[ct][reg] + b;
                h = h > 0.f ? h : 0.f;
                fstage[(rloc + reg) * 128 + col] = h;
            }
        }
        __syncthreads();
        #pragma unroll
        for (int jj = 0; jj < 4; ++jj) {
            int i = tid + jj * 512;        // 2048 float4
            int row = i >> 5, c8 = i & 31;
            if (r0 + row < n) {
                float4 hv = ((const float4*)fstage)[i];
                ((float4*)(outf + (size_t)(r0 + row) * FEAT))[c8] = hv;
                float4 cv;
                cv.x = hv.x >= 0.5f ? 1.f : 0.f; cv.y = hv.y >= 0.5f ? 1.f : 0.f;
                cv.z = hv.z >= 0.5f ? 1.f : 0.f; cv.w = hv.w >= 0.5f ? 1.f : 0.f;
                ((float4*)(out2 + (size_t)(r0 + row) * FEAT))[c8] = cv;
            }
        }
    }
}

extern "C" void kernel_launch(void* const* d_in, const int* in_sizes, int n_in,
                              void* d_out, int out_size, void* d_ws, size_t ws_size,
                              hipStream_t stream) {
    const float* in_feat = (const float*)d_in[0];
    const int*   src     = (const int*)d_in[1];
    const int*   dst     = (const int*)d_in[2];
    const float* W[5] = {(const float*)d_in[3], (const float*)d_in[5], (const float*)d_in[7],
                         (const float*)d_in[9], (const float*)d_in[11]};
    const float* B[5] = {(const float*)d_in[4], (const float*)d_in[6], (const float*)d_in[8],
                         (const float*)d_in[10], (const float*)d_in[12]};
    const int E = in_sizes[1];
    const int N = in_sizes[0] / FEAT;
    const size_t MTOT = (size_t)NPC * NSLICE;         // 3,276,800

    char* ws = (char*)d_ws;
    size_t off = 0;
    auto alloc = [&](size_t bytes) { size_t o = off; off += (bytes + 255) & ~size_t(255); return o; };
    unsigned* partialD = (unsigned*)(ws + alloc(MTOT * 2));
    size_t    pS_off   = alloc(MTOT * 2);
    unsigned* partialS = (unsigned*)(ws + pS_off);
    int*      esrc     = (int*)(ws + pS_off);          // aliases partialS (dead after prep1)
    int*      cursorVT = (int*)(ws + alloc(MTOT * 4));
    _Float16* xhA      = (_Float16*)(ws + alloc((size_t)N * FEAT * 2));
    _Float16* xhB      = (_Float16*)(ws + alloc((size_t)N * FEAT * 2));
    float*    ns       = (float*)(ws + alloc((size_t)N * 4));
    float*    nd       = (float*)(ws + alloc((size_t)N * 4));
    int*      offsc    = (int*)(ws + alloc((size_t)(N + 1) * 4));
    int*      blockSums = (int*)(ws + alloc(1024));
    _Float16* w16t     = (_Float16*)(ws + alloc(5 * 16384 * 2));
    _Float16* wrt      = (_Float16*)(ws + alloc(5 * 16384 * 2));

    float* out_h = (float*)d_out;                     // final h
    float* out_c = out_h + (size_t)N * FEAT;          // threshold output

    const int scanBlocks = NPC / 256;                 // 200
    const int psBlocks = (N * (FEAT / 8) + 255) / 256; // 3125

    hist_kernel<<<2 * NSLICE, 1024, (NPC / 2) * 4, stream>>>(src, dst, partialD, partialS, E);
    prep1_kernel<<<scanBlocks + 320, 256, 0, stream>>>((const unsigned short*)partialD,
                                                       (const unsigned short*)partialS,
                                                       blockSums, ns, nd,
                                                       W[0], W[1], W[2], W[3], W[4],
                                                       w16t, wrt, N, scanBlocks);
    prep2_kernel<<<scanBlocks + psBlocks, 256, 0, stream>>>((const unsigned short*)partialD,
                                                            blockSums, cursorVT, offsc,
                                                            in_feat, ns, xhA, N, scanBlocks);
    fill_kernel<<<(NPC / RANGE_F) * NSLICE, 1024, RANGE_F * 4, stream>>>(src, dst, cursorVT,
                                                                         esrc, E);

    const int layerBlocks = (N + 63) / 64;            // 782

    for (int l = 0; l < 5; ++l) {
        const _Float16* xin = (l & 1) ? xhB : xhA;
        _Float16*       xout = (l & 1) ? xhA : xhB;
        if (l < 4)
            layer_kernel<0><<<layerBlocks, 512, LDS_TOTAL, stream>>>(
                xin, offsc, esrc, nd, ns, w16t + (size_t)l * 16384,
                wrt + (size_t)l * 16384, B[l], xout, nullptr, nullptr, N);
        else
            layer_kernel<1><<<layerBlocks, 512, LDS_TOTAL, stream>>>(
                xin, offsc, esrc, nd, nullptr, w16t + (size_t)l * 16384,
                wrt + (size_t)l * 16384, B[l], nullptr, out_h, out_c, N);
    }
}

// Round 12
// 404.284 us; speedup vs baseline: 8.7282x; 8.7282x over previous
//
#include <hip/hip_runtime.h>

#define FEAT 128
#define NSLICE 64
#define NPC 51200          // padded node count (problem-fixed N=50000)
#define RANGE_F 25600      // fill cursor tile (2 range passes)

typedef _Float16 half8 __attribute__((ext_vector_type(8)));
typedef float f32x4 __attribute__((ext_vector_type(4)));

// ---------- hist: one pass, full-node packed histogram in 102.4KB dynamic LDS ----------
__global__ __launch_bounds__(1024) void hist_kernel(const int* __restrict__ src,
                                                    const int* __restrict__ dst,
                                                    unsigned* __restrict__ partialD,
                                                    unsigned* __restrict__ partialS,
                                                    int E) {
    extern __shared__ unsigned hpk[];                // NPC/2 = 25600 words
    int b = blockIdx.x;
    int halfsel = b >> 6;
    int s = b & 63;
    const int* arr = halfsel ? src : dst;
    unsigned* out = halfsel ? partialS : partialD;
    int tid = threadIdx.x;
    for (int i = tid; i < NPC / 2; i += 1024) hpk[i] = 0;
    __syncthreads();
    int e0 = (int)((long long)E * s / NSLICE);
    int e1 = (int)((long long)E * (s + 1) / NSLICE);
    for (int e = e0 + tid; e < e1; e += 1024) {
        unsigned d = (unsigned)arr[e];
        atomicAdd(&hpk[d >> 1], (d & 1) ? 65536u : 1u);
    }
    __syncthreads();
    size_t wbase = ((size_t)s * NPC) >> 1;
    for (int i = tid; i < NPC / 2; i += 1024) out[wbase + i] = hpk[i];
}

// ---------- prep1: blocks [0,sb): slice sums + norms + blockSums
//                   blocks [sb, sb+320): W fp16 value+residual transpose ----------
__global__ __launch_bounds__(256) void prep1_kernel(const unsigned short* __restrict__ pD,
                                                    const unsigned short* __restrict__ pS,
                                                    int* __restrict__ blockSums,
                                                    float* __restrict__ ns,
                                                    float* __restrict__ nd,
                                                    const float* __restrict__ Wa,
                                                    const float* __restrict__ Wb,
                                                    const float* __restrict__ Wc,
                                                    const float* __restrict__ Wd,
                                                    const float* __restrict__ We,
                                                    _Float16* __restrict__ w16t,
                                                    _Float16* __restrict__ wrt,
                                                    int n, int sb) {
    int tid = threadIdx.x;
    int b = blockIdx.x;
    if (b < sb) {
        __shared__ int buf[256];
        int v = b * 256 + tid;
        int ssum = 0, osum = 0;
        #pragma unroll
        for (int s = 0; s < NSLICE; ++s) {
            ssum += pD[(size_t)s * NPC + v];
            osum += pS[(size_t)s * NPC + v];
        }
        if (v < n) {
            ns[v] = 1.0f / sqrtf((float)(osum < 1 ? 1 : osum));
            nd[v] = 1.0f / sqrtf((float)(ssum < 1 ? 1 : ssum));
        }
        buf[tid] = ssum;
        __syncthreads();
        #pragma unroll
        for (int off = 1; off < 256; off <<= 1) {
            int t = (tid >= off) ? buf[tid - off] : 0;
            __syncthreads();
            buf[tid] += t;
            __syncthreads();
        }
        if (tid == 255) blockSums[b] = buf[255];
    } else {
        int gid = (b - sb) * 256 + tid;              // 0 .. 81919
        int l = gid >> 14;
        int idx = gid & 16383;
        int col = idx >> 7;
        int k = idx & 127;
        const float* Wp = (l == 0) ? Wa : (l == 1) ? Wb : (l == 2) ? Wc : (l == 3) ? Wd : We;
        float w = Wp[k * FEAT + col];
        _Float16 h = (_Float16)w;
        _Float16 r = (_Float16)(w - (float)h);
        w16t[gid] = h;
        wrt[gid] = r;
    }
}

// ---------- prep2: blocks [0,nb): merged scan2+scan3, cursorVT [slice][node] layout
//                   blocks [nb, ...): prescale xh = fp16(in_feat * ns) ----------
__global__ __launch_bounds__(256) void prep2_kernel(const unsigned short* __restrict__ pD,
                                                    const int* __restrict__ blockSums,
                                                    int* __restrict__ cursorVT,
                                                    int* __restrict__ offsc,
                                                    const float* __restrict__ xf,
                                                    const float* __restrict__ ns,
                                                    _Float16* __restrict__ xh,
                                                    int n, int nb) {
    int tid = threadIdx.x;
    int b = blockIdx.x;
    if (b < nb) {
        __shared__ int buf[256];
        int bsv = (tid < nb) ? blockSums[tid] : 0;
        buf[tid] = bsv;
        __syncthreads();
        #pragma unroll
        for (int off = 1; off < 256; off <<= 1) {
            int t = (tid >= off) ? buf[tid - off] : 0;
            __syncthreads();
            buf[tid] += t;
            __syncthreads();
        }
        int myoff = (b > 0) ? buf[b - 1] : 0;
        __syncthreads();
        int v = b * 256 + tid;
        int ssum = 0;
        #pragma unroll
        for (int s = 0; s < NSLICE; ++s) ssum += pD[(size_t)s * NPC + v];
        buf[tid] = ssum;
        __syncthreads();
        #pragma unroll
        for (int off = 1; off < 256; off <<= 1) {
            int t = (tid >= off) ? buf[tid - off] : 0;
            __syncthreads();
            buf[tid] += t;
            __syncthreads();
        }
        int o = myoff + buf[tid] - ssum;
        if (v <= n) offsc[v] = o;      // pad nodes have zero edges -> v==n gets total
        #pragma unroll
        for (int s = 0; s < NSLICE; ++s) {
            int val = pD[(size_t)s * NPC + v];
            cursorVT[(size_t)s * NPC + v] = o;       // coalesced per-s
            o += val;
        }
    } else {
        int i = (b - nb) * 256 + tid;                // one thread per 8 elements
        if (i < n * (FEAT / 8)) {
            int v = i >> 4;
            float w = ns[v];
            float4 t0 = ((const float4*)xf)[i * 2];
            float4 t1 = ((const float4*)xf)[i * 2 + 1];
            half8 h;
            h[0] = (_Float16)(t0.x * w); h[1] = (_Float16)(t0.y * w);
            h[2] = (_Float16)(t0.z * w); h[3] = (_Float16)(t0.w * w);
            h[4] = (_Float16)(t1.x * w); h[5] = (_Float16)(t1.y * w);
            h[6] = (_Float16)(t1.z * w); h[7] = (_Float16)(t1.w * w);
            ((float4*)xh)[i] = __builtin_bit_cast(float4, h);
        }
    }
}

// ---------- fill: 2 range passes, contiguous cursor tile load, XCD-swizzled slices ----------
__global__ __launch_bounds__(1024) void fill_kernel(const int* __restrict__ src,
                                                    const int* __restrict__ dst,
                                                    const int* __restrict__ cursorVT,
                                                    int* __restrict__ esrc, int E) {
    extern __shared__ int cur[];                     // RANGE_F ints = 102.4KB
    int b = blockIdx.x;
    int r = b / NSLICE;
    int inner = b % NSLICE;
    int s = ((inner & 7) << 3) | (inner >> 3);
    int v0 = r * RANGE_F;
    int tid = threadIdx.x;
    const int4* csrc = (const int4*)(cursorVT + (size_t)s * NPC + v0);
    for (int i = tid; i < RANGE_F / 4; i += 1024)
        ((int4*)cur)[i] = csrc[i];
    __syncthreads();
    int e0 = (int)((long long)E * s / NSLICE);
    int e1 = (int)((long long)E * (s + 1) / NSLICE);
    for (int e = e0 + tid; e < e1; e += 1024) {
        unsigned dd = (unsigned)(dst[e] - v0);
        if (dd < RANGE_F) {
            int p = atomicAdd(&cur[dd], 1);
            esrc[p] = src[e];
        }
    }
}

// ---------- aggregation: fp16 gather, fp32 accumulate, fp16 m output ----------
__global__ __launch_bounds__(256) void agg_kernel(const _Float16* __restrict__ x,
                                                  const int* __restrict__ offs,
                                                  const int* __restrict__ esrc,
                                                  const float* __restrict__ nd,
                                                  _Float16* __restrict__ m, int n) {
    int gid = blockIdx.x * blockDim.x + threadIdx.x;
    int v = gid >> 6;
    if (v >= n) return;
    int lane = threadIdx.x & 63;
    int q = lane >> 4;       // quarter 0..3: independent edge stream, stride 4
    int c = lane & 15;       // 16 lanes x 16B cover a 128-half row
    int s0 = offs[v], s1 = offs[v + 1];
    float a0[8] = {0,0,0,0,0,0,0,0};
    float a1[8] = {0,0,0,0,0,0,0,0};
    float a2[8] = {0,0,0,0,0,0,0,0};
    float a3[8] = {0,0,0,0,0,0,0,0};
    int j = s0 + q;
    for (; j + 12 < s1; j += 16) {
        int e0 = esrc[j], e1 = esrc[j + 4], e2 = esrc[j + 8], e3 = esrc[j + 12];
        float4 r0 = ((const float4*)(x + (size_t)e0 * FEAT))[c];
        float4 r1 = ((const float4*)(x + (size_t)e1 * FEAT))[c];
        float4 r2 = ((const float4*)(x + (size_t)e2 * FEAT))[c];
        float4 r3 = ((const float4*)(x + (size_t)e3 * FEAT))[c];
        half8 h0 = __builtin_bit_cast(half8, r0);
        half8 h1 = __builtin_bit_cast(half8, r1);
        half8 h2 = __builtin_bit_cast(half8, r2);
        half8 h3 = __builtin_bit_cast(half8, r3);
        #pragma unroll
        for (int k = 0; k < 8; ++k) {
            a0[k] += (float)h0[k];
            a1[k] += (float)h1[k];
            a2[k] += (float)h2[k];
            a3[k] += (float)h3[k];
        }
    }
    for (; j < s1; j += 4) {
        int e0 = esrc[j];
        float4 r0 = ((const float4*)(x + (size_t)e0 * FEAT))[c];
        half8 h0 = __builtin_bit_cast(half8, r0);
        #pragma unroll
        for (int k = 0; k < 8; ++k) a0[k] += (float)h0[k];
    }
    float r[8];
    #pragma unroll
    for (int k = 0; k < 8; ++k) r[k] = (a0[k] + a1[k]) + (a2[k] + a3[k]);
    #pragma unroll
    for (int k = 0; k < 8; ++k) {
        r[k] += __shfl_xor(r[k], 16);
        r[k] += __shfl_xor(r[k], 32);
    }
    if (lane < 16) {
        float sc = nd[v];
        half8 h;
        #pragma unroll
        for (int k = 0; k < 8; ++k) h[k] = (_Float16)(r[k] * sc);
        ((float4*)(m + (size_t)v * FEAT))[c] = __builtin_bit_cast(float4, h);
    }
}

// ---------- GEMM: MFMA f16, m fp16 in (Ar==0), W value+residual; coalesced epilogue ----------
// 32x128 tile, 256 threads (4 waves: 2 row x 2 col), 72KB LDS -> 2 blocks/CU.
// acc = A16*W16 + A16*Wr   (m pre-quantized fp16; W residual kept)
template<int MODE>   // 0: relu*ns -> fp16   1: last layer (fp32 h + threshold)
__global__ __launch_bounds__(256) void gemm_kernel(const _Float16* __restrict__ M,
                                                   const _Float16* __restrict__ w16t,
                                                   const _Float16* __restrict__ wrt,
                                                   const float* __restrict__ bias,
                                                   const float* __restrict__ nsv,
                                                   _Float16* __restrict__ outh,
                                                   float* __restrict__ outf,
                                                   float* __restrict__ out2, int n) {
    __shared__ _Float16 sh[36864];     // 72KB: A16[4096] W16[16384] Wr[16384]
    _Float16* A16s = sh;
    _Float16* W16s = sh + 4096;
    _Float16* Wrs  = sh + 20480;
    int tid = threadIdx.x;
    int r0 = blockIdx.x * 32;

    // stage W (value+residual), XOR-swizzled 16B chunks: chunk ^= (col&7)
    #pragma unroll
    for (int j = 0; j < 8; ++j) {
        int i = tid + j * 256;             // 2048 float4 per array
        int col = i >> 4, ch = i & 15;
        int d = col * 16 + (ch ^ (col & 7));
        ((float4*)W16s)[d] = ((const float4*)w16t)[i];
        ((float4*)Wrs)[d]  = ((const float4*)wrt)[i];
    }
    // stage A rows r0..r0+31: fp16 direct, swizzled
    #pragma unroll
    for (int j = 0; j < 2; ++j) {
        int i = tid + j * 256;             // 512 float4 (8 halves each)
        int row = i >> 4, c8 = i & 15;
        int gr = r0 + row;
        float4 v = make_float4(0.f, 0.f, 0.f, 0.f);
        if (gr < n) v = ((const float4*)(M + (size_t)gr * FEAT))[c8];
        int d = row * 128 + ((c8 ^ (row & 7)) << 3);
        *(float4*)(A16s + d) = v;
    }
    __syncthreads();

    int lane = tid & 63;
    int w = tid >> 6;
    int l15 = lane & 15;
    int q = lane >> 4;
    int rbase = (w & 1) * 16 + l15;        // A-frag row
    int cbase = (w >> 1) * 64;             // wave's 64-col strip

    f32x4 acc[4] = {{0.f,0.f,0.f,0.f},{0.f,0.f,0.f,0.f},{0.f,0.f,0.f,0.f},{0.f,0.f,0.f,0.f}};
    #pragma unroll
    for (int ks = 0; ks < 4; ++ks) {
        int chunk = ks * 4 + q;
        int aoff = rbase * 128 + ((chunk ^ (rbase & 7)) << 3);
        half8 a16 = *(const half8*)(A16s + aoff);
        #pragma unroll
        for (int ct = 0; ct < 4; ++ct) {
            int col = cbase + ct * 16 + l15;
            int boff = col * 128 + ((chunk ^ (col & 7)) << 3);
            half8 b16 = *(const half8*)(W16s + boff);
            half8 br  = *(const half8*)(Wrs + boff);
            acc[ct] = __builtin_amdgcn_mfma_f32_16x16x32_f16(a16, b16, acc[ct], 0, 0, 0);
            acc[ct] = __builtin_amdgcn_mfma_f32_16x16x32_f16(a16, br,  acc[ct], 0, 0, 0);
        }
    }

    // epilogue via LDS restage -> coalesced float4 global stores.
    // C/D layout: col=lane&15, row=(lane>>4)*4+reg
    int rloc = (w & 1) * 16 + q * 4;
    __syncthreads();                       // all MFMA reads of sh done; safe to reuse
    if (MODE == 0) {
        _Float16* hstage = sh;             // 32x128 fp16 = 8KB
        float scv[4];
        #pragma unroll
        for (int reg = 0; reg < 4; ++reg) {
            int row = r0 + rloc + reg;
            scv[reg] = (row < n) ? nsv[row] : 1.0f;
        }
        #pragma unroll
        for (int ct = 0; ct < 4; ++ct) {
            int col = cbase + ct * 16 + l15;
            float b = bias[col];
            #pragma unroll
            for (int reg = 0; reg < 4; ++reg) {
                float h = acc[ct][reg] + b;
                h = h > 0.f ? h : 0.f;
                hstage[(rloc + reg) * 128 + col] = (_Float16)(h * scv[reg]);
            }
        }
        __syncthreads();
        #pragma unroll
        for (int j = 0; j < 2; ++j) {
            int i = tid + j * 256;         // 512 float4 (8 halfs each)
            int row = i >> 4, c16 = i & 15;
            if (r0 + row < n)
                ((float4*)(outh + (size_t)(r0 + row) * FEAT))[c16] =
                    ((const float4*)hstage)[i];
        }
    } else {
        float* fstage = (float*)sh;        // 32x128 fp32 = 16KB
        #pragma unroll
        for (int ct = 0; ct < 4; ++ct) {
            int col = cbase + ct * 16 + l15;
            float b = bias[col];
            #pragma unroll
            for (int reg = 0; reg < 4; ++reg) {
                float h = acc[ct][reg] + b;
                h = h > 0.f ? h : 0.f;
                fstage[(rloc + reg) * 128 + col] = h;
            }
        }
        __syncthreads();
        #pragma unroll
        for (int j = 0; j < 4; ++j) {
            int i = tid + j * 256;         // 1024 float4
            int row = i >> 5, c8 = i & 31;
            if (r0 + row < n) {
                float4 hv = ((const float4*)fstage)[i];
                ((float4*)(outf + (size_t)(r0 + row) * FEAT))[c8] = hv;
                float4 cv;
                cv.x = hv.x >= 0.5f ? 1.f : 0.f; cv.y = hv.y >= 0.5f ? 1.f : 0.f;
                cv.z = hv.z >= 0.5f ? 1.f : 0.f; cv.w = hv.w >= 0.5f ? 1.f : 0.f;
                ((float4*)(out2 + (size_t)(r0 + row) * FEAT))[c8] = cv;
            }
        }
    }
}

extern "C" void kernel_launch(void* const* d_in, const int* in_sizes, int n_in,
                              void* d_out, int out_size, void* d_ws, size_t ws_size,
                              hipStream_t stream) {
    const float* in_feat = (const float*)d_in[0];
    const int*   src     = (const int*)d_in[1];
    const int*   dst     = (const int*)d_in[2];
    const float* W[5] = {(const float*)d_in[3], (const float*)d_in[5], (const float*)d_in[7],
                         (const float*)d_in[9], (const float*)d_in[11]};
    const float* B[5] = {(const float*)d_in[4], (const float*)d_in[6], (const float*)d_in[8],
                         (const float*)d_in[10], (const float*)d_in[12]};
    const int E = in_sizes[1];
    const int N = in_sizes[0] / FEAT;
    const size_t MTOT = (size_t)NPC * NSLICE;         // 3,276,800

    char* ws = (char*)d_ws;
    size_t off = 0;
    auto alloc = [&](size_t bytes) { size_t o = off; off += (bytes + 255) & ~size_t(255); return o; };
    unsigned* partialD = (unsigned*)(ws + alloc(MTOT * 2));
    size_t    pS_off   = alloc(MTOT * 2);
    unsigned* partialS = (unsigned*)(ws + pS_off);
    int*      esrc     = (int*)(ws + pS_off);          // aliases partialS (dead after prep1)
    int*      cursorVT = (int*)(ws + alloc(MTOT * 4));
    _Float16* xh       = (_Float16*)(ws + alloc((size_t)N * FEAT * 2));
    _Float16* mh       = (_Float16*)(ws + alloc((size_t)N * FEAT * 2));
    float*    ns       = (float*)(ws + alloc((size_t)N * 4));
    float*    nd       = (float*)(ws + alloc((size_t)N * 4));
    int*      offsc    = (int*)(ws + alloc((size_t)(N + 1) * 4));
    int*      blockSums = (int*)(ws + alloc(1024));
    _Float16* w16t     = (_Float16*)(ws + alloc(5 * 16384 * 2));
    _Float16* wrt      = (_Float16*)(ws + alloc(5 * 16384 * 2));

    float* out_h = (float*)d_out;                     // final h
    float* out_c = out_h + (size_t)N * FEAT;          // threshold output

    const int scanBlocks = NPC / 256;                 // 200
    const int psBlocks = (N * (FEAT / 8) + 255) / 256; // 3125

    hist_kernel<<<2 * NSLICE, 1024, (NPC / 2) * 4, stream>>>(src, dst, partialD, partialS, E);
    prep1_kernel<<<scanBlocks + 320, 256, 0, stream>>>((const unsigned short*)partialD,
                                                       (const unsigned short*)partialS,
                                                       blockSums, ns, nd,
                                                       W[0], W[1], W[2], W[3], W[4],
                                                       w16t, wrt, N, scanBlocks);
    prep2_kernel<<<scanBlocks + psBlocks, 256, 0, stream>>>((const unsigned short*)partialD,
                                                            blockSums, cursorVT, offsc,
                                                            in_feat, ns, xh, N, scanBlocks);
    fill_kernel<<<(NPC / RANGE_F) * NSLICE, 1024, RANGE_F * 4, stream>>>(src, dst, cursorVT,
                                                                         esrc, E);

    const int agg_blocks = (int)(((size_t)N * 64 + 255) / 256);   // 12500
    const int gemm_blocks = (N + 31) / 32;                        // 1563

    for (int l = 0; l < 5; ++l) {
        agg_kernel<<<agg_blocks, 256, 0, stream>>>(xh, offsc, esrc, nd, mh, N);
        if (l < 4)
            gemm_kernel<0><<<gemm_blocks, 256, 0, stream>>>(mh, w16t + (size_t)l * 16384,
                                                            wrt + (size_t)l * 16384, B[l], ns,
                                                            xh, nullptr, nullptr, N);
        else
            gemm_kernel<1><<<gemm_blocks, 256, 0, stream>>>(mh, w16t + (size_t)l * 16384,
                                                            wrt + (size_t)l * 16384, B[l], nullptr,
                                                            nullptr, out_h, out_c, N);
    }
}